// Round 2
// baseline (771.673 us; speedup 1.0000x reference)
//
#include <hip/hip_runtime.h>
#include <hip/hip_bf16.h>

// Shifted-window attention, b=1, h=w=256, c=128, ns=8 -> 64 windows of 1024 tokens.
// The reference rolls axes (w, c); the c-roll cancels exactly, the w-roll is a
// +16 (mod 256) column gather, and output scatter address == input gather address.
//
// Round 2: 8 waves/block (512 thr, 16 q-rows/wave, QBLK=128) -> 16 waves/CU,
// and register-double-buffered mask prefetch (issue kv+1's mask loads before
// staging kv, consume next iteration) to take mask latency off the critical path.

typedef __attribute__((ext_vector_type(8))) short bhalf8;   // 8 x bf16
typedef __attribute__((ext_vector_type(4))) float f4;
typedef __attribute__((ext_vector_type(4))) int i4;

#define MFMA16(a, b, c) __builtin_amdgcn_mfma_f32_16x16x32_bf16((a), (b), (c), 0, 0, 0)

__device__ __forceinline__ unsigned short f2bf(float f) {
    unsigned u = __builtin_bit_cast(unsigned, f);
    return (unsigned short)((u + 0x7fffu + ((u >> 16) & 1u)) >> 16);  // RNE
}

// global element offset of window-row r (0..1023) for window (i,j); channel 0
__device__ __forceinline__ int rowOff(int i, int j, int r) {
    int y = i * 32 + (r >> 5);
    int x = (j * 32 + (r & 31) + 16) & 255;   // the surviving W-roll
    return ((y << 8) + x) << 7;               // *(C=128)
}

// load 16 mask f32 (frag layout) for s-tile starting at S0 (element offset into mrow)
#define MLOAD(MN, S0) do {                                                    \
    const float* mp_ = mrow + (S0) + l15;                                     \
    _Pragma("unroll") for (int sf_ = 0; sf_ < 4; ++sf_)                       \
        _Pragma("unroll") for (int r_ = 0; r_ < 4; ++r_)                      \
            MN[sf_ * 4 + r_] = mp_[r_ * 1024 + sf_ * 16];                     \
} while (0)

#define BODY(KV, MC, MN) do {                                                 \
    const int s0 = (KV) * 64;                                                 \
    /* issue next iteration's mask loads first (lands during staging) */      \
    MLOAD(MN, (((KV) + 1) & 15) * 64);                                        \
    /* ---- stage K tile (64x128 -> bf16, swizzled) ---- */                   \
    {                                                                         \
        const int rl = tid >> 4, ch0 = (tid & 15) * 8;                        \
        _Pragma("unroll") for (int p = 0; p < 2; ++p) {                       \
            int row = p * 32 + rl;                                            \
            const float* src = Kg + rowOff(wi, wj, s0 + row) + ch0;           \
            f4 a = *(const f4*)src;                                           \
            f4 b = *(const f4*)(src + 4);                                     \
            union { unsigned short us[8]; i4 v; } pk;                         \
            _Pragma("unroll") for (int u = 0; u < 4; ++u) {                   \
                pk.us[u] = f2bf(a[u]); pk.us[u + 4] = f2bf(b[u]); }           \
            *(i4*)(smem + row * 256 + ((ch0 * 2) ^ ((row & 7) << 4))) = pk.v; \
        }                                                                     \
        /* ---- stage V transposed (Vt[ch][s], swizzled) ---- */              \
        _Pragma("unroll") for (int p = 0; p < 2; ++p) {                       \
            int task = tid + p * 512;                                         \
            int ch = task & 127, sb = task >> 7;                              \
            union { unsigned short us[8]; i4 v; } pk;                         \
            _Pragma("unroll") for (int u = 0; u < 8; ++u)                     \
                pk.us[u] = f2bf(Vg[rowOff(wi, wj, s0 + sb * 8 + u) + ch]);    \
            *(i4*)(smem + 16384 + ch * 128 + ((sb * 16) ^ ((ch & 7) << 4))) = pk.v; \
        }                                                                     \
    }                                                                         \
    __syncthreads();                                                          \
    /* ---- C-init from prefetched mask regs: acc = mask*sqrt(128) ---- */    \
    f4 acc[4];                                                                \
    _Pragma("unroll") for (int sf = 0; sf < 4; ++sf) {                        \
        f4 t;                                                                 \
        t[0] = MC[sf * 4 + 0] * SCALE; t[1] = MC[sf * 4 + 1] * SCALE;         \
        t[2] = MC[sf * 4 + 2] * SCALE; t[3] = MC[sf * 4 + 3] * SCALE;         \
        acc[sf] = t;                                                          \
    }                                                                         \
    /* ---- S = Q K^T (+mask via C-init) ---- */                              \
    _Pragma("unroll") for (int sf = 0; sf < 4; ++sf) {                        \
        int row = sf * 16 + l15;                                              \
        const unsigned char* rb = smem + row * 256;                           \
        _Pragma("unroll") for (int ks = 0; ks < 4; ++ks) {                    \
            bhalf8 kb = *(const bhalf8*)(rb + ((ks * 64 + l4 * 16) ^ ((row & 7) << 4))); \
            acc[sf] = MFMA16(qf[ks], kb, acc[sf]);                            \
        }                                                                     \
    }                                                                         \
    /* ---- p = exp(S), accumulate row-sums, write P (per-wave LDS) ---- */   \
    _Pragma("unroll") for (int sf = 0; sf < 4; ++sf)                          \
        _Pragma("unroll") for (int r = 0; r < 4; ++r) {                       \
            float p = __builtin_amdgcn_exp2f(acc[sf][r] * K1);                \
            lpart[r] += p;                                                    \
            int q = l4 * 4 + r, s = sf * 16 + l15;                            \
            *(unsigned short*)(Plds + q * 128 + ((s * 2) ^ ((q & 7) << 4))) = f2bf(p); \
        }                                                                     \
    /* ---- O += P V ---- */                                                  \
    bhalf8 pa[2];                                                             \
    {                                                                         \
        int q = l15;                                                          \
        _Pragma("unroll") for (int ks = 0; ks < 2; ++ks)                      \
            pa[ks] = *(const bhalf8*)(Plds + q * 128 + ((ks * 64 + l4 * 16) ^ ((q & 7) << 4))); \
    }                                                                         \
    _Pragma("unroll") for (int cf = 0; cf < 8; ++cf) {                        \
        int row = cf * 16 + l15;                                              \
        const unsigned char* rb = smem + 16384 + row * 128;                   \
        _Pragma("unroll") for (int ks = 0; ks < 2; ++ks) {                    \
            bhalf8 vb = *(const bhalf8*)(rb + ((ks * 64 + l4 * 16) ^ ((row & 7) << 4))); \
            Oacc[cf] = MFMA16(pa[ks], vb, Oacc[cf]);                          \
        }                                                                     \
    }                                                                         \
    __syncthreads();                                                          \
} while (0)

__global__ __launch_bounds__(512, 4)
void swin_attn_kernel(const float* __restrict__ Qg, const float* __restrict__ Kg,
                      const float* __restrict__ Vg, const float* __restrict__ Mg,
                      float* __restrict__ Og) {
    // LDS: [0,16K) K tile | [16K,32K) Vt tile | [32K,48K) per-wave P (2 KB each)
    // Q-stage prologue reuses [0,32K).
    __shared__ __align__(16) unsigned char smem[49152];

    const int tid  = threadIdx.x;
    const int lane = tid & 63;
    const int wv   = tid >> 6;          // wave 0..7
    const int l15  = lane & 15;
    const int l4   = lane >> 4;         // 0..3

    // XCD swizzle: all 8 q-tiles of a window share g%8 -> same XCD L2
    const int g     = blockIdx.x;
    const int w_idx = (g & 7) + ((g >> 6) << 3);   // window 0..63
    const int tq    = (g >> 3) & 7;                // q-tile 0..7
    const int wi = w_idx >> 3, wj = w_idx & 7;
    const int q0 = tq * 128;

    const float SCALE = 11.313708498984760f;               // sqrt(128)
    const float K1    = 1.4426950408889634f / SCALE;       // log2(e)/sqrt(128)

    // ---------------- stage Q tile (128 x 128, bf16, XOR-swizzled) -------------
    {
        const int rl  = tid >> 4;
        const int ch0 = (tid & 15) * 8;
#pragma unroll
        for (int p = 0; p < 4; ++p) {
            int row = p * 32 + rl;
            const float* src = Qg + rowOff(wi, wj, q0 + row) + ch0;
            f4 a = *(const f4*)src;
            f4 b = *(const f4*)(src + 4);
            union { unsigned short us[8]; i4 v; } pk;
#pragma unroll
            for (int u = 0; u < 4; ++u) { pk.us[u] = f2bf(a[u]); pk.us[u + 4] = f2bf(b[u]); }
            *(i4*)(smem + row * 256 + ((ch0 * 2) ^ ((row & 7) << 4))) = pk.v;
        }
    }
    __syncthreads();

    // Q fragments: wave wv owns q rows [wv*16, wv*16+16)
    bhalf8 qf[4];
    {
        int row = wv * 16 + l15;
#pragma unroll
        for (int ks = 0; ks < 4; ++ks)
            qf[ks] = *(const bhalf8*)(smem + row * 256 + ((ks * 64 + l4 * 16) ^ ((row & 7) << 4)));
    }
    __syncthreads();

    f4 Oacc[8];
#pragma unroll
    for (int cf = 0; cf < 8; ++cf) Oacc[cf] = (f4){0.f, 0.f, 0.f, 0.f};
    float lpart[4] = {0.f, 0.f, 0.f, 0.f};

    unsigned char* Plds = smem + 32768 + wv * 2048;        // [16 q][64 s] bf16, swizzled
    // mask row pointer for this wave's q rows (lane groups add r*1024 inside MLOAD)
    const float* mrow = Mg + ((size_t)w_idx << 20) + (size_t)(q0 + wv * 16 + l4 * 4) * 1024;

    float mA[16], mB[16];
    MLOAD(mA, 0);   // mask for kv=0

    for (int kv2 = 0; kv2 < 16; kv2 += 2) {
        BODY(kv2, mA, mB);
        BODY(kv2 + 1, mB, mA);
    }

    // row sums: reduce over the 16 lanes of each l4 group
#pragma unroll
    for (int t = 0; t < 4; ++t) {
        float v = lpart[t];
        v += __shfl_xor(v, 1); v += __shfl_xor(v, 2);
        v += __shfl_xor(v, 4); v += __shfl_xor(v, 8);
        lpart[t] = 1.0f / v;
    }

    // write out (scatter address == gather address; 64B-coalesced per 16-lane group)
#pragma unroll
    for (int r = 0; r < 4; ++r) {
        int rg = q0 + wv * 16 + l4 * 4 + r;
        float* dst = Og + rowOff(wi, wj, rg);
        float rin = lpart[r];
#pragma unroll
        for (int cf = 0; cf < 8; ++cf)
            dst[cf * 16 + l15] = Oacc[cf][r] * rin;
    }
}

extern "C" void kernel_launch(void* const* d_in, const int* in_sizes, int n_in,
                              void* d_out, int out_size, void* d_ws, size_t ws_size,
                              hipStream_t stream) {
    const float* q = (const float*)d_in[0];
    const float* k = (const float*)d_in[1];
    const float* v = (const float*)d_in[2];
    const float* m = (const float*)d_in[3];
    float* out = (float*)d_out;
    hipLaunchKernelGGL(swin_attn_kernel, dim3(512), dim3(512), 0, stream, q, k, v, m, out);
}